// Round 19
// baseline (406.002 us; speedup 1.0000x reference)
//
#include <hip/hip_runtime.h>
#include <hip/hip_bf16.h>

#define D_MODEL 1024
#define SEQ 2048
#define NH 16
#define HSZ 64
#define DFF_ 4096

typedef __attribute__((ext_vector_type(8))) short short8;
typedef __attribute__((ext_vector_type(4))) short short4v;
typedef __attribute__((ext_vector_type(4))) float f32x4;

static __device__ __forceinline__ short f2bf(float f) {
  unsigned u = __builtin_bit_cast(unsigned, f);
  u = u + 0x7fffu + ((u >> 16) & 1u);
  return (short)(u >> 16);
}

static __device__ __forceinline__ unsigned packbf2(float a, float b) {
  return (unsigned)(unsigned short)f2bf(a) | ((unsigned)(unsigned short)f2bf(b) << 16);
}

static __device__ __forceinline__ f32x4 mfma16(short8 a, short8 b, f32x4 c) {
  return __builtin_amdgcn_mfma_f32_16x16x32_bf16(a, b, c, 0, 0, 0);
}

static __device__ __forceinline__ void gld16(const short* g, short* l) {
  __builtin_amdgcn_global_load_lds((const __attribute__((address_space(1))) void*)g,
                                   (__attribute__((address_space(3))) void*)l, 16, 0, 0);
}

#define SM_SCALE 0.18033688011112042f /* 0.125 * log2(e) */
#define VMW(n) asm volatile("s_waitcnt vmcnt(" #n ")" ::: "memory")

// ---------------- weight transpose/convert kernels ----------------
__global__ void transpose_qkv_kernel(const float* __restrict__ Wq, const float* __restrict__ Wk,
                                     const float* __restrict__ Wv, short* __restrict__ dst) {
  __shared__ float tile[32][33];
  const int z = blockIdx.z;
  const int which = z >> 4, hh = z & 15;
  const float* src = (which == 0 ? Wq : which == 1 ? Wk : Wv) + (long)hh * (D_MODEL * HSZ);
  const int c0 = blockIdx.x * 32, r0 = blockIdx.y * 32;
  const int tx = threadIdx.x, ty = threadIdx.y;
#pragma unroll
  for (int i = 0; i < 4; ++i)
    tile[ty + 8 * i][tx] = src[(long)(r0 + ty + 8 * i) * HSZ + c0 + tx];
  __syncthreads();
#pragma unroll
  for (int i = 0; i < 4; ++i)
    dst[((long)which * 1024 + hh * 64 + c0 + ty + 8 * i) * D_MODEL + r0 + tx] =
        f2bf(tile[tx][ty + 8 * i]);
}

// fused Wp/W1/W2 transpose: flat grid, block-range dispatch
__global__ void transpose_all_kernel(const float* __restrict__ Wp, short* __restrict__ WpT,
                                     const float* __restrict__ W1, short* __restrict__ W1T,
                                     const float* __restrict__ W2, short* __restrict__ W2T) {
  __shared__ float tile[32][33];
  int id = blockIdx.x;
  const float* src;
  short* dst;
  int R, C, bx, by;
  if (id < 1024) {
    src = Wp; dst = WpT; R = 1024; C = 1024; bx = id & 31; by = id >> 5;
  } else if (id < 5120) {
    id -= 1024;
    src = W1; dst = W1T; R = 1024; C = 4096; bx = id & 127; by = id >> 7;
  } else {
    id -= 5120;
    src = W2; dst = W2T; R = 4096; C = 1024; bx = id & 31; by = id >> 5;
  }
  const int c0 = bx * 32, r0 = by * 32;
  const int tx = threadIdx.x, ty = threadIdx.y;
#pragma unroll
  for (int i = 0; i < 4; ++i)
    tile[ty + 8 * i][tx] = src[(long)(r0 + ty + 8 * i) * C + c0 + tx];
  __syncthreads();
#pragma unroll
  for (int i = 0; i < 4; ++i)
    dst[(long)(c0 + ty + 8 * i) * R + r0 + tx] = f2bf(tile[tx][ty + 8 * i]);
}

// V: [B,H,S,HS] -> [B,H,HS,S] (bf16)
__global__ void v_transpose_kernel(const short* __restrict__ vb, short* __restrict__ vt) {
  __shared__ short tile[64 * 72];
  const int bh = blockIdx.y;
  const int t0 = blockIdx.x * 64;
  const long base = (long)bh * SEQ * HSZ;
  const int tid = threadIdx.x;
  const int r = tid >> 3, c = (tid & 7) * 8;
#pragma unroll
  for (int it = 0; it < 2; ++it) {
    const int rr = r + it * 32;
    *(short8*)&tile[rr * 72 + c] = *(const short8*)(vb + base + (long)(t0 + rr) * HSZ + c);
  }
  __syncthreads();
#pragma unroll
  for (int it = 0; it < 2; ++it) {
    const int rr = r + it * 32;  // hs row
    short8 o;
#pragma unroll
    for (int u = 0; u < 8; ++u) o[u] = tile[(c + u) * 72 + rr];
    *(short8*)(vt + base + (long)rr * SEQ + t0 + c) = o;
  }
}

// ---------------- layernorm (f32 in -> bf16 out) ----------------
__global__ void ln_kernel(const float* __restrict__ x, const float* __restrict__ w,
                          const float* __restrict__ b, short* __restrict__ out) {
  const int row = blockIdx.x;
  const float* xr = x + (size_t)row * D_MODEL;
  const int t = threadIdx.x;  // 256
  float4 v = *(const float4*)(xr + t * 4);
  float s = v.x + v.y + v.z + v.w;
  float s2 = v.x * v.x + v.y * v.y + v.z * v.z + v.w * v.w;
#pragma unroll
  for (int o = 1; o < 64; o <<= 1) {
    s += __shfl_xor(s, o, 64);
    s2 += __shfl_xor(s2, o, 64);
  }
  __shared__ float ps[8];
  const int lane = t & 63, wid = t >> 6;
  if (lane == 0) { ps[wid] = s; ps[wid + 4] = s2; }
  __syncthreads();
  s = ps[0] + ps[1] + ps[2] + ps[3];
  s2 = ps[4] + ps[5] + ps[6] + ps[7];
  const float mu = s * (1.0f / D_MODEL);
  const float var = s2 * (1.0f / D_MODEL) - mu * mu;
  const float rs = rsqrtf(var + 1e-5f);
  float4 wv = *(const float4*)(w + t * 4);
  float4 bv = *(const float4*)(b + t * 4);
  short4v o4;
  o4[0] = f2bf((v.x - mu) * rs * wv.x + bv.x);
  o4[1] = f2bf((v.y - mu) * rs * wv.y + bv.y);
  o4[2] = f2bf((v.z - mu) * rs * wv.z + bv.z);
  o4[3] = f2bf((v.w - mu) * rs * wv.w + bv.w);
  *(short4v*)(out + (size_t)row * D_MODEL + t * 4) = o4;
}

// ---------------- GEMM: BM x 256 tile, BK=64, 8 waves (2M x 4N), phased ----
// (banked kernel — used for qkv and ffn1)
template <int MODE, int BM>
__global__ __launch_bounds__(512, 2) void gemm_kernel(
    const short* __restrict__ A, const short* __restrict__ Bt, const int K,
    const float* __restrict__ c0, const float* __restrict__ c1,
    const float* __restrict__ c2, const float* __restrict__ res,
    void* __restrict__ o0, void* __restrict__ o1, void* __restrict__ o2) {
  constexpr int NPH = BM / 64;   // phases per K-tile (4 or 2)
  constexpr int NA = BM / 64;    // A stage chunks (8KB each)
  constexpr int NTOT = NA + 4;   // total stage chunks per K-tile
  constexpr int PER = NTOT / NPH;
  constexpr int HM = BM / 2;
  __shared__ short As[2][BM * 64];
  __shared__ short Bs[2][256 * 64];
  const long r0 = (long)blockIdx.y * BM;
  const long n0 = (long)blockIdx.x * 256;
  const int tid = threadIdx.x;
  const int lane = tid & 63, wid = tid >> 6;
  const int wm = wid >> 2, wn = wid & 3;
  const int l16 = lane & 15, lg = lane >> 4;

  long offA[NA], offB[4];
#pragma unroll
  for (int i = 0; i < NA; ++i) {
    const int c = tid + i * 512;
    const int lam = c >> 3, s = c & 7;
    const int cch = lam >> 6, rho = lam & 63;
    const int g = cch * 32 + (rho & 31) + ((rho >> 5) ? HM : 0);
    offA[i] = (long)(r0 + g) * K + ((s ^ (lam & 7)) << 3);
  }
#pragma unroll
  for (int i = 0; i < 4; ++i) {
    const int c = tid + i * 512;
    const int row = c >> 3, s = c & 7;
    offB[i] = (long)(n0 + row) * K + ((s ^ (row & 7)) << 3);
  }

  f32x4 acc[2 * NPH][4];
#pragma unroll
  for (int m = 0; m < 2 * NPH; ++m)
#pragma unroll
    for (int n = 0; n < 4; ++n) {
      f32x4 z = {0.f, 0.f, 0.f, 0.f};
      acc[m][n] = z;
    }

  const int x7 = l16 & 7;
  const int sw0 = (lg ^ x7) * 8, sw1 = ((4 + lg) ^ x7) * 8;

#define STG(j, kt, buf)                                                      \
  {                                                                          \
    if ((j) < 4)                                                             \
      gld16(Bt + offB[(j)] + (kt), &Bs[buf][(tid + (j)*512) * 8]);           \
    else                                                                     \
      gld16(A + offA[(j)-4] + (kt), &As[buf][(tid + ((j)-4) * 512) * 8]);    \
  }

#define GPHASE(P, ENDSTMT)                                                   \
  {                                                                          \
    short8 af[2][2];                                                         \
    _Pragma("unroll") for (int mm = 0; mm < 2; ++mm) {                       \
      const int lam = (P)*64 + wm * 32 + mm * 16 + l16;                      \
      af[mm][0] = *(const short8*)&Ap[lam * 64 + sw0];                       \
      af[mm][1] = *(const short8*)&Ap[lam * 64 + sw1];                       \
    }                                                                        \
    if ((P) == 0) {                                                          \
      _Pragma("unroll") for (int n = 0; n < 4; ++n) {                        \
        const int r = (wn * 64 + n * 16 + l16) * 64;                         \
        bf[n][0] = *(const short8*)&Bp[r + sw0];                             \
        bf[n][1] = *(const short8*)&Bp[r + sw1];                             \
      }                                                                      \
    }                                                                        \
    if (st) {                                                                \
      _Pragma("unroll") for (int j = (P)*PER; j < ((P) + 1) * PER; ++j)      \
          STG(j, ktn, nb);                                                   \
    }                                                                        \
    asm volatile("s_waitcnt lgkmcnt(0)" ::: "memory");                       \
    __builtin_amdgcn_sched_barrier(0);                                       \
    __builtin_amdgcn_s_setprio(1);                                           \
    _Pragma("unroll") for (int kk = 0; kk < 2; ++kk)                         \
        _Pragma("unroll") for (int mm = 0; mm < 2; ++mm)                     \
        _Pragma("unroll") for (int n = 0; n < 4; ++n) acc[2 * (P) + mm][n] = \
        mfma16(af[mm][kk], bf[n][kk], acc[2 * (P) + mm][n]);                 \
    __builtin_amdgcn_s_setprio(0);                                           \
    ENDSTMT;                                                                 \
    __builtin_amdgcn_s_barrier();                                            \
  }

  const int NT = K >> 6;
#pragma unroll
  for (int j = 0; j < NTOT; ++j) STG(j, 0, 0);
  if constexpr (BM == 256) VMW(3); else VMW(1);
  __builtin_amdgcn_s_barrier();

  for (int t = 0; t < NT; ++t) {
    const int cur = t & 1, nb = cur ^ 1;
    const short* Ap = As[cur];
    const short* Bp = Bs[cur];
    const bool st = (t + 1 < NT);
    const int ktn = (t + 1) << 6;
    short8 bf[4][2];
    if constexpr (BM == 256) {
      GPHASE(0, { if (st) VMW(4); else VMW(2); });
      GPHASE(1, { if (st) VMW(5); else VMW(1); });
      GPHASE(2, { if (st) VMW(6); else VMW(0); });
      GPHASE(3, { if (st) VMW(3); });
    } else {
      GPHASE(0, { if (st) VMW(3); else VMW(0); });
      GPHASE(1, { if (st) VMW(1); });
    }
  }
#undef GPHASE
#undef STG

#pragma unroll
  for (int m = 0; m < 2 * NPH; ++m) {
    const long rowb = r0 + wm * HM + m * 16 + lg * 4;
#pragma unroll
    for (int n = 0; n < 4; ++n) {
      const long col = n0 + wn * 64 + n * 16 + l16;
#pragma unroll
      for (int j = 0; j < 4; ++j) {
        float val = acc[m][n][j];
        const long rr = rowb + j;
        if (MODE == 0) {
          const int c10 = (int)col & 1023;
          const int which = (int)col >> 10;
          const float* bb = which == 0 ? c0 : which == 1 ? c1 : c2;
          short* oo = (short*)(which == 0 ? o0 : which == 1 ? o1 : o2);
          val += bb[c10];
          if (which == 0) val *= SM_SCALE;  // fold softmax scale into q
          const long bidx = rr >> 11, sidx = rr & 2047;
          const int h = c10 >> 6, hs = c10 & 63;
          oo[(((bidx * NH) + h) * SEQ + sidx) * HSZ + hs] = f2bf(val);
        } else if (MODE == 2) {
          val += c0[col];
          const float g = 0.5f * val * (1.0f + erff(val * 0.70710678118654752f));
          ((short*)o0)[rr * DFF_ + col] = f2bf(g);
        } else {
          val += c0[col] + res[rr * D_MODEL + col];
          ((float*)o0)[rr * D_MODEL + col] = val;
        }
      }
    }
  }
}

// ------- GEMM 128x128, BK=64, 8 waves (4M x 2N), 64KB LDS -> 2 blocks/CU -------
// One phase per K-tile: {stage 4 chunks of t+1 ; 12 b128 frag reads ;
// lgkmcnt(0)+sched_barrier ; 16 MFMA ; vmcnt(0) ; barrier}. Used for proj/ffn2.
__global__ __launch_bounds__(512, 2) void gemm128_kernel(
    const short* __restrict__ A, const short* __restrict__ Bt, const int K,
    const float* __restrict__ c0, const float* __restrict__ res,
    float* __restrict__ o0) {
  __shared__ short As[2][128 * 64];
  __shared__ short Bs[2][128 * 64];
  const long r0 = (long)blockIdx.y * 128;
  const long n0 = (long)blockIdx.x * 128;
  const int tid = threadIdx.x;
  const int lane = tid & 63, wid = tid >> 6;
  const int wm = wid >> 1, wn = wid & 1;
  const int l16 = lane & 15, lg = lane >> 4;

  long offA[2], offB[2];
#pragma unroll
  for (int i = 0; i < 2; ++i) {
    const int c = tid + i * 512;
    const int lam = c >> 3, s = c & 7;
    offA[i] = (long)(r0 + lam) * K + ((s ^ (lam & 7)) << 3);
    offB[i] = (long)(n0 + lam) * K + ((s ^ (lam & 7)) << 3);
  }

  f32x4 acc[2][4];
#pragma unroll
  for (int m = 0; m < 2; ++m)
#pragma unroll
    for (int n = 0; n < 4; ++n) {
      f32x4 z = {0.f, 0.f, 0.f, 0.f};
      acc[m][n] = z;
    }

  const int x7 = l16 & 7;
  const int sw0 = (lg ^ x7) * 8, sw1 = ((4 + lg) ^ x7) * 8;

#define STG8(kt, buf)                                                       \
  {                                                                         \
    _Pragma("unroll") for (int i = 0; i < 2; ++i) {                         \
      gld16(Bt + offB[i] + (kt), &Bs[buf][(tid + i * 512) * 8]);            \
      gld16(A + offA[i] + (kt), &As[buf][(tid + i * 512) * 8]);             \
    }                                                                       \
  }

  const int NT = K >> 6;
  STG8(0, 0);
  VMW(0);
  __builtin_amdgcn_s_barrier();

  for (int t = 0; t < NT; ++t) {
    const int cur = t & 1, nb = cur ^ 1;
    const short* Ap = As[cur];
    const short* Bp = Bs[cur];
    const bool st = (t + 1 < NT);
    if (st) STG8((t + 1) << 6, nb);
    short8 af[2][2], bf[4][2];
#pragma unroll
    for (int mm = 0; mm < 2; ++mm) {
      const int r = (wm * 32 + mm * 16 + l16) * 64;
      af[mm][0] = *(const short8*)&Ap[r + sw0];
      af[mm][1] = *(const short8*)&Ap[r + sw1];
    }
#pragma unroll
    for (int n = 0; n < 4; ++n) {
      const int r = (wn * 64 + n * 16 + l16) * 64;
      bf[n][0] = *(const short8*)&Bp[r + sw0];
      bf[n][1] = *(const short8*)&Bp[r + sw1];
    }
    asm volatile("s_waitcnt lgkmcnt(0)" ::: "memory");
    __builtin_amdgcn_sched_barrier(0);
    __builtin_amdgcn_s_setprio(1);
#pragma unroll
    for (int kk = 0; kk < 2; ++kk)
#pragma unroll
      for (int mm = 0; mm < 2; ++mm)
#pragma unroll
        for (int n = 0; n < 4; ++n)
          acc[mm][n] = mfma16(af[mm][kk], bf[n][kk], acc[mm][n]);
    __builtin_amdgcn_s_setprio(0);
    if (st) VMW(0);
    __builtin_amdgcn_s_barrier();
  }
#undef STG8

#pragma unroll
  for (int mm = 0; mm < 2; ++mm) {
    const long rowb = r0 + wm * 32 + mm * 16 + lg * 4;
#pragma unroll
    for (int n = 0; n < 4; ++n) {
      const long col = n0 + wn * 64 + n * 16 + l16;
#pragma unroll
      for (int j = 0; j < 4; ++j) {
        const long rr = rowb + j;
        o0[rr * D_MODEL + col] = acc[mm][n][j] + c0[col] + res[rr * D_MODEL + col];
      }
    }
  }
}

// ---------------- flash attention: swapped QK^T, O^T accumulation ----------------
__global__ void attn_kernel(const short* __restrict__ q, const short* __restrict__ k,
                            const short* __restrict__ vt, short* __restrict__ att) {
  const int qt = (SEQ / 128 - 1) - (int)blockIdx.y;  // heavy blocks first
  const int bh = blockIdx.x;
  const int b = bh >> 4, h = bh & 15;
  const int tid = threadIdx.x;
  const int lane = tid & 63, wq = tid >> 6;
  const int l16 = lane & 15, lg = lane >> 4;
  const long base = (long)bh * SEQ * HSZ;

  __shared__ short Ks[64 * 64];   // [t][d] swizzled
  __shared__ short Vts[64 * 64];  // [hs][t] swizzled
  __shared__ short Ps[4 * 32 * 72];
  short* Psw = &Ps[wq * 32 * 72];

  const int R0 = qt * 128 + wq * 32;

  short8 qf[2][2];
#pragma unroll
  for (int qn = 0; qn < 2; ++qn)
#pragma unroll
    for (int kk = 0; kk < 2; ++kk)
      qf[qn][kk] =
          *(const short8*)(q + base + (long)(R0 + qn * 16 + l16) * HSZ + kk * 32 + lg * 8);

  float m_[2] = {-INFINITY, -INFINITY};
  float l_[2] = {0.f, 0.f};
  f32x4 oacc[2][4];
#pragma unroll
  for (int qn = 0; qn < 2; ++qn)
#pragma unroll
    for (int hf = 0; hf < 4; ++hf) {
      f32x4 z = {0.f, 0.f, 0.f, 0.f};
      oacc[qn][hf] = z;
    }

  const int srow = tid >> 3, wg = tid & 7;
  const int swc = (wg ^ (srow & 7)) * 8;  // swizzled store col
  const int x7 = l16 & 7;
  const int rc0 = (lg ^ x7) * 8, rc1 = ((4 + lg) ^ x7) * 8;  // swizzled read cols
  const int tend = (qt + 1) * 128;

  for (int t0 = 0; t0 < tend; t0 += 64) {
    __syncthreads();
#pragma unroll
    for (int it = 0; it < 2; ++it) {
      const int r = srow + it * 32;
      const short8 kv = *(const short8*)(k + base + (long)(t0 + r) * HSZ + wg * 8);
      const short8 vv = *(const short8*)(vt + base + (long)r * SEQ + t0 + wg * 8);
      *(short8*)&Ks[r * 64 + swc] = kv;
      *(short8*)&Vts[r * 64 + swc] = vv;
    }
    __syncthreads();

    if (t0 <= R0 + 31) {
      // S^T = K Q^T (already in log2 units)
      f32x4 sf[4][2];
#pragma unroll
      for (int tt = 0; tt < 4; ++tt)
#pragma unroll
        for (int qn = 0; qn < 2; ++qn) {
          f32x4 z = {0.f, 0.f, 0.f, 0.f};
          sf[tt][qn] = z;
        }
      __builtin_amdgcn_s_setprio(1);
#pragma unroll
      for (int kk = 0; kk < 2; ++kk)
#pragma unroll
        for (int tt = 0; tt < 4; ++tt) {
          short8 kf = *(const short8*)&Ks[(tt * 16 + l16) * 64 + (kk ? rc1 : rc0)];
#pragma unroll
          for (int qn = 0; qn < 2; ++qn) sf[tt][qn] = mfma16(kf, qf[qn][kk], sf[tt][qn]);
        }
      __builtin_amdgcn_s_setprio(0);

      const bool domask = (t0 + 63 > R0);
      if (domask) {
        const int tb = t0 + lg * 4;
#pragma unroll
        for (int tt = 0; tt < 4; ++tt)
#pragma unroll
          for (int qn = 0; qn < 2; ++qn) {
            const int qg = R0 + qn * 16 + l16;
#pragma unroll
            for (int j = 0; j < 4; ++j)
              if (tb + tt * 16 + j > qg) sf[tt][qn][j] = -INFINITY;
          }
      }

      float mx[2];
#pragma unroll
      for (int qn = 0; qn < 2; ++qn) {
        float m0 = sf[0][qn][0];
#pragma unroll
        for (int tt = 0; tt < 4; ++tt)
#pragma unroll
          for (int j = 0; j < 4; ++j) m0 = fmaxf(m0, sf[tt][qn][j]);
        m0 = fmaxf(m0, __shfl_xor(m0, 16, 64));
        m0 = fmaxf(m0, __shfl_xor(m0, 32, 64));
        mx[qn] = m0;
      }
      const int ok = (mx[0] <= m_[0] + 8.f) && (mx[1] <= m_[1] + 8.f);
      if (!__all(ok)) {
#pragma unroll
        for (int qn = 0; qn < 2; ++qn) {
          const float mnew = fmaxf(m_[qn], mx[qn]);
          const float rc = exp2f(m_[qn] - mnew);
          m_[qn] = mnew;
          l_[qn] *= rc;
#pragma unroll
          for (int hf = 0; hf < 4; ++hf)
#pragma unroll
            for (int j = 0; j < 4; ++j) oacc[qn][hf][j] *= rc;
        }
      }
#pragma unroll
      for (int qn = 0; qn < 2; ++qn) {
        float sum = 0.f;
#pragma unroll
        for (int tt = 0; tt < 4; ++tt)
#pragma unroll
          for (int j = 0; j < 4; ++j) {
            const float p = exp2f(sf[tt][qn][j] - m_[qn]);
            sf[tt][qn][j] = p;
            sum += p;
          }
        l_[qn] += sum;
      }

      // P -> per-wave LDS
#pragma unroll
      for (int qn = 0; qn < 2; ++qn)
#pragma unroll
        for (int tt = 0; tt < 4; ++tt) {
          const int ro = (qn * 16 + l16) * 72 + tt * 16 + lg * 4;
          *(unsigned*)&Psw[ro] = packbf2(sf[tt][qn][0], sf[tt][qn][1]);
          *(unsigned*)&Psw[ro + 2] = packbf2(sf[tt][qn][2], sf[tt][qn][3]);
        }

      // O^T += V^T P^T
      __builtin_amdgcn_s_setprio(1);
#pragma unroll
      for (int kk = 0; kk < 2; ++kk) {
        short8 pa[2];
#pragma unroll
        for (int qn = 0; qn < 2; ++qn)
          pa[qn] = *(const short8*)&Psw[(qn * 16 + l16) * 72 + kk * 32 + lg * 8];
#pragma unroll
        for (int hf = 0; hf < 4; ++hf) {
          short8 vf = *(const short8*)&Vts[(hf * 16 + l16) * 64 + (kk ? rc1 : rc0)];
#pragma unroll
          for (int qn = 0; qn < 2; ++qn)
            oacc[qn][hf] = mfma16(vf, pa[qn], oacc[qn][hf]);
        }
      }
      __builtin_amdgcn_s_setprio(0);
    }
  }

#pragma unroll
  for (int qn = 0; qn < 2; ++qn) {
    float lt = l_[qn];
    lt += __shfl_xor(lt, 16, 64);
    lt += __shfl_xor(lt, 32, 64);
    const float inv = 1.0f / lt;
    const long row = R0 + qn * 16 + l16;
#pragma unroll
    for (int hf = 0; hf < 4; ++hf) {
      short4v o4;
#pragma unroll
      for (int j = 0; j < 4; ++j) o4[j] = f2bf(oacc[qn][hf][j] * inv);
      *(short4v*)(att + ((long)b * SEQ + row) * D_MODEL + h * HSZ + hf * 16 + lg * 4) = o4;
    }
  }
}

// ---------------- launch ----------------
extern "C" void kernel_launch(void* const* d_in, const int* in_sizes, int n_in,
                              void* d_out, int out_size, void* d_ws, size_t ws_size,
                              hipStream_t stream) {
  const float* x = (const float*)d_in[0];
  const float* Wq = (const float*)d_in[1];
  const float* bq = (const float*)d_in[2];
  const float* Wk = (const float*)d_in[3];
  const float* bk = (const float*)d_in[4];
  const float* Wv = (const float*)d_in[5];
  const float* bv = (const float*)d_in[6];
  const float* Wp = (const float*)d_in[7];
  const float* bp = (const float*)d_in[8];
  const float* g1 = (const float*)d_in[9];
  const float* be1 = (const float*)d_in[10];
  const float* g2 = (const float*)d_in[11];
  const float* be2 = (const float*)d_in[12];
  const float* W1 = (const float*)d_in[13];
  const float* b1 = (const float*)d_in[14];
  const float* W2 = (const float*)d_in[15];
  const float* b2 = (const float*)d_in[16];
  float* out = (float*)d_out;
  char* ws = (char*)d_ws;

  if (ws_size < 209715200ull) return;

  short* WqkvT = (short*)(ws + 0);       // [3072][1024] bf16
  short* WpT = (short*)(ws + 6291456);   // [1024][1024]
  short* W1T = (short*)(ws + 8388608);   // [4096][1024]
  short* W2T = (short*)(ws + 16777216);  // [1024][4096]
  short* xn = (short*)(ws + 25165824);   // [8192][1024] (ln out; vt aliases after qkv)
  short* vt = (short*)(ws + 25165824);   // [B,H,HS,S] (aliases xn)
  short* qb = (short*)(ws + 41943040);   // [B,H,S,HS]
  short* kb = (short*)(ws + 58720256);
  short* vb = (short*)(ws + 75497472);
  short* att = (short*)(ws + 92274688);    // [8192][1024]
  float* x1 = (float*)(ws + 109051904);    // [8192][1024] f32
  short* hb = (short*)(ws + 142606336);    // [8192][4096]

  dim3 tb(32, 8);
  transpose_qkv_kernel<<<dim3(2, 32, 48), tb, 0, stream>>>(Wq, Wk, Wv, WqkvT);
  transpose_all_kernel<<<9216, tb, 0, stream>>>(Wp, WpT, W1, W1T, W2, W2T);
  ln_kernel<<<8192, 256, 0, stream>>>(x, g1, be1, xn);
  gemm_kernel<0, 128><<<dim3(12, 64), 512, 0, stream>>>(xn, WqkvT, 1024, bq, bk, bv,
                                                        nullptr, qb, kb, vb);
  v_transpose_kernel<<<dim3(32, 64), 256, 0, stream>>>(vb, vt);
  attn_kernel<<<dim3(64, 16), 256, 0, stream>>>(qb, kb, vt, att);
  gemm128_kernel<<<dim3(8, 64), 512, 0, stream>>>(att, WpT, 1024, bp, x, x1);
  ln_kernel<<<8192, 256, 0, stream>>>(x1, g2, be2, xn);
  gemm_kernel<2, 256><<<dim3(16, 32), 512, 0, stream>>>(xn, W1T, 1024, b1, nullptr,
                                                        nullptr, nullptr, hb, nullptr,
                                                        nullptr);
  gemm128_kernel<<<dim3(8, 64), 512, 0, stream>>>(hb, W2T, 4096, b2, x1, out);
}

// Round 20
// 404.705 us; speedup vs baseline: 1.0032x; 1.0032x over previous
//
#include <hip/hip_runtime.h>
#include <hip/hip_bf16.h>

#define D_MODEL 1024
#define SEQ 2048
#define NH 16
#define HSZ 64
#define DFF_ 4096

typedef __attribute__((ext_vector_type(8))) short short8;
typedef __attribute__((ext_vector_type(4))) short short4v;
typedef __attribute__((ext_vector_type(4))) float f32x4;

static __device__ __forceinline__ short f2bf(float f) {
  unsigned u = __builtin_bit_cast(unsigned, f);
  u = u + 0x7fffu + ((u >> 16) & 1u);
  return (short)(u >> 16);
}

static __device__ __forceinline__ unsigned packbf2(float a, float b) {
  return (unsigned)(unsigned short)f2bf(a) | ((unsigned)(unsigned short)f2bf(b) << 16);
}

static __device__ __forceinline__ f32x4 mfma16(short8 a, short8 b, f32x4 c) {
  return __builtin_amdgcn_mfma_f32_16x16x32_bf16(a, b, c, 0, 0, 0);
}

static __device__ __forceinline__ void gld16(const short* g, short* l) {
  __builtin_amdgcn_global_load_lds((const __attribute__((address_space(1))) void*)g,
                                   (__attribute__((address_space(3))) void*)l, 16, 0, 0);
}

#define SM_SCALE 0.18033688011112042f /* 0.125 * log2(e) */
#define VMW(n) asm volatile("s_waitcnt vmcnt(" #n ")" ::: "memory")

// ---------------- weight transpose/convert kernels ----------------
__global__ void transpose_qkv_kernel(const float* __restrict__ Wq, const float* __restrict__ Wk,
                                     const float* __restrict__ Wv, short* __restrict__ dst) {
  __shared__ float tile[32][33];
  const int z = blockIdx.z;
  const int which = z >> 4, hh = z & 15;
  const float* src = (which == 0 ? Wq : which == 1 ? Wk : Wv) + (long)hh * (D_MODEL * HSZ);
  const int c0 = blockIdx.x * 32, r0 = blockIdx.y * 32;
  const int tx = threadIdx.x, ty = threadIdx.y;
#pragma unroll
  for (int i = 0; i < 4; ++i)
    tile[ty + 8 * i][tx] = src[(long)(r0 + ty + 8 * i) * HSZ + c0 + tx];
  __syncthreads();
#pragma unroll
  for (int i = 0; i < 4; ++i)
    dst[((long)which * 1024 + hh * 64 + c0 + ty + 8 * i) * D_MODEL + r0 + tx] =
        f2bf(tile[tx][ty + 8 * i]);
}

// fused Wp/W1/W2 transpose: flat grid, block-range dispatch
__global__ void transpose_all_kernel(const float* __restrict__ Wp, short* __restrict__ WpT,
                                     const float* __restrict__ W1, short* __restrict__ W1T,
                                     const float* __restrict__ W2, short* __restrict__ W2T) {
  __shared__ float tile[32][33];
  int id = blockIdx.x;
  const float* src;
  short* dst;
  int R, C, bx, by;
  if (id < 1024) {
    src = Wp; dst = WpT; R = 1024; C = 1024; bx = id & 31; by = id >> 5;
  } else if (id < 5120) {
    id -= 1024;
    src = W1; dst = W1T; R = 1024; C = 4096; bx = id & 127; by = id >> 7;
  } else {
    id -= 5120;
    src = W2; dst = W2T; R = 4096; C = 1024; bx = id & 31; by = id >> 5;
  }
  const int c0 = bx * 32, r0 = by * 32;
  const int tx = threadIdx.x, ty = threadIdx.y;
#pragma unroll
  for (int i = 0; i < 4; ++i)
    tile[ty + 8 * i][tx] = src[(long)(r0 + ty + 8 * i) * C + c0 + tx];
  __syncthreads();
#pragma unroll
  for (int i = 0; i < 4; ++i)
    dst[(long)(c0 + ty + 8 * i) * R + r0 + tx] = f2bf(tile[tx][ty + 8 * i]);
}

// V: [B,H,S,HS] -> [B,H,HS,S] (bf16)
__global__ void v_transpose_kernel(const short* __restrict__ vb, short* __restrict__ vt) {
  __shared__ short tile[64 * 72];
  const int bh = blockIdx.y;
  const int t0 = blockIdx.x * 64;
  const long base = (long)bh * SEQ * HSZ;
  const int tid = threadIdx.x;
  const int r = tid >> 3, c = (tid & 7) * 8;
#pragma unroll
  for (int it = 0; it < 2; ++it) {
    const int rr = r + it * 32;
    *(short8*)&tile[rr * 72 + c] = *(const short8*)(vb + base + (long)(t0 + rr) * HSZ + c);
  }
  __syncthreads();
#pragma unroll
  for (int it = 0; it < 2; ++it) {
    const int rr = r + it * 32;  // hs row
    short8 o;
#pragma unroll
    for (int u = 0; u < 8; ++u) o[u] = tile[(c + u) * 72 + rr];
    *(short8*)(vt + base + (long)rr * SEQ + t0 + c) = o;
  }
}

// ---------------- layernorm (f32 in -> bf16 out) ----------------
__global__ void ln_kernel(const float* __restrict__ x, const float* __restrict__ w,
                          const float* __restrict__ b, short* __restrict__ out) {
  const int row = blockIdx.x;
  const float* xr = x + (size_t)row * D_MODEL;
  const int t = threadIdx.x;  // 256
  float4 v = *(const float4*)(xr + t * 4);
  float s = v.x + v.y + v.z + v.w;
  float s2 = v.x * v.x + v.y * v.y + v.z * v.z + v.w * v.w;
#pragma unroll
  for (int o = 1; o < 64; o <<= 1) {
    s += __shfl_xor(s, o, 64);
    s2 += __shfl_xor(s2, o, 64);
  }
  __shared__ float ps[8];
  const int lane = t & 63, wid = t >> 6;
  if (lane == 0) { ps[wid] = s; ps[wid + 4] = s2; }
  __syncthreads();
  s = ps[0] + ps[1] + ps[2] + ps[3];
  s2 = ps[4] + ps[5] + ps[6] + ps[7];
  const float mu = s * (1.0f / D_MODEL);
  const float var = s2 * (1.0f / D_MODEL) - mu * mu;
  const float rs = rsqrtf(var + 1e-5f);
  float4 wv = *(const float4*)(w + t * 4);
  float4 bv = *(const float4*)(b + t * 4);
  short4v o4;
  o4[0] = f2bf((v.x - mu) * rs * wv.x + bv.x);
  o4[1] = f2bf((v.y - mu) * rs * wv.y + bv.y);
  o4[2] = f2bf((v.z - mu) * rs * wv.z + bv.z);
  o4[3] = f2bf((v.w - mu) * rs * wv.w + bv.w);
  *(short4v*)(out + (size_t)row * D_MODEL + t * 4) = o4;
}

// ---------------- GEMM: BM x 256 tile, BK=64, 8 waves (2M x 4N), phased ----
// (banked kernel — used for qkv and ffn1)
template <int MODE, int BM>
__global__ __launch_bounds__(512, 2) void gemm_kernel(
    const short* __restrict__ A, const short* __restrict__ Bt, const int K,
    const float* __restrict__ c0, const float* __restrict__ c1,
    const float* __restrict__ c2, const float* __restrict__ res,
    void* __restrict__ o0, void* __restrict__ o1, void* __restrict__ o2) {
  constexpr int NPH = BM / 64;   // phases per K-tile (4 or 2)
  constexpr int NA = BM / 64;    // A stage chunks (8KB each)
  constexpr int NTOT = NA + 4;   // total stage chunks per K-tile
  constexpr int PER = NTOT / NPH;
  constexpr int HM = BM / 2;
  __shared__ short As[2][BM * 64];
  __shared__ short Bs[2][256 * 64];
  const long r0 = (long)blockIdx.y * BM;
  const long n0 = (long)blockIdx.x * 256;
  const int tid = threadIdx.x;
  const int lane = tid & 63, wid = tid >> 6;
  const int wm = wid >> 2, wn = wid & 3;
  const int l16 = lane & 15, lg = lane >> 4;

  long offA[NA], offB[4];
#pragma unroll
  for (int i = 0; i < NA; ++i) {
    const int c = tid + i * 512;
    const int lam = c >> 3, s = c & 7;
    const int cch = lam >> 6, rho = lam & 63;
    const int g = cch * 32 + (rho & 31) + ((rho >> 5) ? HM : 0);
    offA[i] = (long)(r0 + g) * K + ((s ^ (lam & 7)) << 3);
  }
#pragma unroll
  for (int i = 0; i < 4; ++i) {
    const int c = tid + i * 512;
    const int row = c >> 3, s = c & 7;
    offB[i] = (long)(n0 + row) * K + ((s ^ (row & 7)) << 3);
  }

  f32x4 acc[2 * NPH][4];
#pragma unroll
  for (int m = 0; m < 2 * NPH; ++m)
#pragma unroll
    for (int n = 0; n < 4; ++n) {
      f32x4 z = {0.f, 0.f, 0.f, 0.f};
      acc[m][n] = z;
    }

  const int x7 = l16 & 7;
  const int sw0 = (lg ^ x7) * 8, sw1 = ((4 + lg) ^ x7) * 8;

#define STG(j, kt, buf)                                                      \
  {                                                                          \
    if ((j) < 4)                                                             \
      gld16(Bt + offB[(j)] + (kt), &Bs[buf][(tid + (j)*512) * 8]);           \
    else                                                                     \
      gld16(A + offA[(j)-4] + (kt), &As[buf][(tid + ((j)-4) * 512) * 8]);    \
  }

#define GPHASE(P, ENDSTMT)                                                   \
  {                                                                          \
    short8 af[2][2];                                                         \
    _Pragma("unroll") for (int mm = 0; mm < 2; ++mm) {                       \
      const int lam = (P)*64 + wm * 32 + mm * 16 + l16;                      \
      af[mm][0] = *(const short8*)&Ap[lam * 64 + sw0];                       \
      af[mm][1] = *(const short8*)&Ap[lam * 64 + sw1];                       \
    }                                                                        \
    if ((P) == 0) {                                                          \
      _Pragma("unroll") for (int n = 0; n < 4; ++n) {                        \
        const int r = (wn * 64 + n * 16 + l16) * 64;                         \
        bf[n][0] = *(const short8*)&Bp[r + sw0];                             \
        bf[n][1] = *(const short8*)&Bp[r + sw1];                             \
      }                                                                      \
    }                                                                        \
    if (st) {                                                                \
      _Pragma("unroll") for (int j = (P)*PER; j < ((P) + 1) * PER; ++j)      \
          STG(j, ktn, nb);                                                   \
    }                                                                        \
    asm volatile("s_waitcnt lgkmcnt(0)" ::: "memory");                       \
    __builtin_amdgcn_sched_barrier(0);                                       \
    __builtin_amdgcn_s_setprio(1);                                           \
    _Pragma("unroll") for (int kk = 0; kk < 2; ++kk)                         \
        _Pragma("unroll") for (int mm = 0; mm < 2; ++mm)                     \
        _Pragma("unroll") for (int n = 0; n < 4; ++n) acc[2 * (P) + mm][n] = \
        mfma16(af[mm][kk], bf[n][kk], acc[2 * (P) + mm][n]);                 \
    __builtin_amdgcn_s_setprio(0);                                           \
    ENDSTMT;                                                                 \
    __builtin_amdgcn_s_barrier();                                            \
  }

  const int NT = K >> 6;
#pragma unroll
  for (int j = 0; j < NTOT; ++j) STG(j, 0, 0);
  if constexpr (BM == 256) VMW(3); else VMW(1);
  __builtin_amdgcn_s_barrier();

  for (int t = 0; t < NT; ++t) {
    const int cur = t & 1, nb = cur ^ 1;
    const short* Ap = As[cur];
    const short* Bp = Bs[cur];
    const bool st = (t + 1 < NT);
    const int ktn = (t + 1) << 6;
    short8 bf[4][2];
    if constexpr (BM == 256) {
      GPHASE(0, { if (st) VMW(4); else VMW(2); });
      GPHASE(1, { if (st) VMW(5); else VMW(1); });
      GPHASE(2, { if (st) VMW(6); else VMW(0); });
      GPHASE(3, { if (st) VMW(3); });
    } else {
      GPHASE(0, { if (st) VMW(3); else VMW(0); });
      GPHASE(1, { if (st) VMW(1); });
    }
  }
#undef GPHASE
#undef STG

#pragma unroll
  for (int m = 0; m < 2 * NPH; ++m) {
    const long rowb = r0 + wm * HM + m * 16 + lg * 4;
#pragma unroll
    for (int n = 0; n < 4; ++n) {
      const long col = n0 + wn * 64 + n * 16 + l16;
#pragma unroll
      for (int j = 0; j < 4; ++j) {
        float val = acc[m][n][j];
        const long rr = rowb + j;
        if (MODE == 0) {
          const int c10 = (int)col & 1023;
          const int which = (int)col >> 10;
          const float* bb = which == 0 ? c0 : which == 1 ? c1 : c2;
          short* oo = (short*)(which == 0 ? o0 : which == 1 ? o1 : o2);
          val += bb[c10];
          if (which == 0) val *= SM_SCALE;  // fold softmax scale into q
          const long bidx = rr >> 11, sidx = rr & 2047;
          const int h = c10 >> 6, hs = c10 & 63;
          oo[(((bidx * NH) + h) * SEQ + sidx) * HSZ + hs] = f2bf(val);
        } else if (MODE == 2) {
          val += c0[col];
          const float g = 0.5f * val * (1.0f + erff(val * 0.70710678118654752f));
          ((short*)o0)[rr * DFF_ + col] = f2bf(g);
        } else {
          val += c0[col] + res[rr * D_MODEL + col];
          ((float*)o0)[rr * D_MODEL + col] = val;
        }
      }
    }
  }
}

// ------- GEMM 128x128, BK=64, 8 waves (4M x 2N), 64KB LDS -> 2 blocks/CU -------
// One phase per K-tile: {stage 4 chunks of t+1 ; 12 b128 frag reads ;
// lgkmcnt(0)+sched_barrier ; 16 MFMA ; vmcnt(0) ; barrier}. Used for proj/ffn2.
__global__ __launch_bounds__(512, 2) void gemm128_kernel(
    const short* __restrict__ A, const short* __restrict__ Bt, const int K,
    const float* __restrict__ c0, const float* __restrict__ res,
    float* __restrict__ o0) {
  __shared__ short As[2][128 * 64];
  __shared__ short Bs[2][128 * 64];
  const long r0 = (long)blockIdx.y * 128;
  const long n0 = (long)blockIdx.x * 128;
  const int tid = threadIdx.x;
  const int lane = tid & 63, wid = tid >> 6;
  const int wm = wid >> 1, wn = wid & 1;
  const int l16 = lane & 15, lg = lane >> 4;

  long offA[2], offB[2];
#pragma unroll
  for (int i = 0; i < 2; ++i) {
    const int c = tid + i * 512;
    const int lam = c >> 3, s = c & 7;
    offA[i] = (long)(r0 + lam) * K + ((s ^ (lam & 7)) << 3);
    offB[i] = (long)(n0 + lam) * K + ((s ^ (lam & 7)) << 3);
  }

  f32x4 acc[2][4];
#pragma unroll
  for (int m = 0; m < 2; ++m)
#pragma unroll
    for (int n = 0; n < 4; ++n) {
      f32x4 z = {0.f, 0.f, 0.f, 0.f};
      acc[m][n] = z;
    }

  const int x7 = l16 & 7;
  const int sw0 = (lg ^ x7) * 8, sw1 = ((4 + lg) ^ x7) * 8;

#define STG8(kt, buf)                                                       \
  {                                                                         \
    _Pragma("unroll") for (int i = 0; i < 2; ++i) {                         \
      gld16(Bt + offB[i] + (kt), &Bs[buf][(tid + i * 512) * 8]);            \
      gld16(A + offA[i] + (kt), &As[buf][(tid + i * 512) * 8]);             \
    }                                                                       \
  }

  const int NT = K >> 6;
  STG8(0, 0);
  VMW(0);
  __builtin_amdgcn_s_barrier();

  for (int t = 0; t < NT; ++t) {
    const int cur = t & 1, nb = cur ^ 1;
    const short* Ap = As[cur];
    const short* Bp = Bs[cur];
    const bool st = (t + 1 < NT);
    if (st) STG8((t + 1) << 6, nb);
    short8 af[2][2], bf[4][2];
#pragma unroll
    for (int mm = 0; mm < 2; ++mm) {
      const int r = (wm * 32 + mm * 16 + l16) * 64;
      af[mm][0] = *(const short8*)&Ap[r + sw0];
      af[mm][1] = *(const short8*)&Ap[r + sw1];
    }
#pragma unroll
    for (int n = 0; n < 4; ++n) {
      const int r = (wn * 64 + n * 16 + l16) * 64;
      bf[n][0] = *(const short8*)&Bp[r + sw0];
      bf[n][1] = *(const short8*)&Bp[r + sw1];
    }
    asm volatile("s_waitcnt lgkmcnt(0)" ::: "memory");
    __builtin_amdgcn_sched_barrier(0);
    __builtin_amdgcn_s_setprio(1);
#pragma unroll
    for (int kk = 0; kk < 2; ++kk)
#pragma unroll
      for (int mm = 0; mm < 2; ++mm)
#pragma unroll
        for (int n = 0; n < 4; ++n)
          acc[mm][n] = mfma16(af[mm][kk], bf[n][kk], acc[mm][n]);
    __builtin_amdgcn_s_setprio(0);
    if (st) VMW(0);
    __builtin_amdgcn_s_barrier();
  }
#undef STG8

#pragma unroll
  for (int mm = 0; mm < 2; ++mm) {
    const long rowb = r0 + wm * 32 + mm * 16 + lg * 4;
#pragma unroll
    for (int n = 0; n < 4; ++n) {
      const long col = n0 + wn * 64 + n * 16 + l16;
#pragma unroll
      for (int j = 0; j < 4; ++j) {
        const long rr = rowb + j;
        o0[rr * D_MODEL + col] = acc[mm][n][j] + c0[col] + res[rr * D_MODEL + col];
      }
    }
  }
}

// ---------------- flash attention: swapped QK^T, O^T accumulation ----------------
__global__ void attn_kernel(const short* __restrict__ q, const short* __restrict__ k,
                            const short* __restrict__ vt, short* __restrict__ att) {
  const int qt = (SEQ / 128 - 1) - (int)blockIdx.y;  // heavy blocks first
  const int bh = blockIdx.x;
  const int b = bh >> 4, h = bh & 15;
  const int tid = threadIdx.x;
  const int lane = tid & 63, wq = tid >> 6;
  const int l16 = lane & 15, lg = lane >> 4;
  const long base = (long)bh * SEQ * HSZ;

  __shared__ short Ks[64 * 64];   // [t][d] swizzled
  __shared__ short Vts[64 * 64];  // [hs][t] swizzled
  __shared__ short Ps[4 * 32 * 72];
  short* Psw = &Ps[wq * 32 * 72];

  const int R0 = qt * 128 + wq * 32;

  short8 qf[2][2];
#pragma unroll
  for (int qn = 0; qn < 2; ++qn)
#pragma unroll
    for (int kk = 0; kk < 2; ++kk)
      qf[qn][kk] =
          *(const short8*)(q + base + (long)(R0 + qn * 16 + l16) * HSZ + kk * 32 + lg * 8);

  float m_[2] = {-INFINITY, -INFINITY};
  float l_[2] = {0.f, 0.f};
  f32x4 oacc[2][4];
#pragma unroll
  for (int qn = 0; qn < 2; ++qn)
#pragma unroll
    for (int hf = 0; hf < 4; ++hf) {
      f32x4 z = {0.f, 0.f, 0.f, 0.f};
      oacc[qn][hf] = z;
    }

  const int srow = tid >> 3, wg = tid & 7;
  const int swc = (wg ^ (srow & 7)) * 8;  // swizzled store col
  const int x7 = l16 & 7;
  const int rc0 = (lg ^ x7) * 8, rc1 = ((4 + lg) ^ x7) * 8;  // swizzled read cols
  const int tend = (qt + 1) * 128;

  for (int t0 = 0; t0 < tend; t0 += 64) {
    __syncthreads();
#pragma unroll
    for (int it = 0; it < 2; ++it) {
      const int r = srow + it * 32;
      const short8 kv = *(const short8*)(k + base + (long)(t0 + r) * HSZ + wg * 8);
      const short8 vv = *(const short8*)(vt + base + (long)r * SEQ + t0 + wg * 8);
      *(short8*)&Ks[r * 64 + swc] = kv;
      *(short8*)&Vts[r * 64 + swc] = vv;
    }
    __syncthreads();

    if (t0 <= R0 + 31) {
      // S^T = K Q^T (already in log2 units)
      f32x4 sf[4][2];
#pragma unroll
      for (int tt = 0; tt < 4; ++tt)
#pragma unroll
        for (int qn = 0; qn < 2; ++qn) {
          f32x4 z = {0.f, 0.f, 0.f, 0.f};
          sf[tt][qn] = z;
        }
      __builtin_amdgcn_s_setprio(1);
#pragma unroll
      for (int kk = 0; kk < 2; ++kk)
#pragma unroll
        for (int tt = 0; tt < 4; ++tt) {
          short8 kf = *(const short8*)&Ks[(tt * 16 + l16) * 64 + (kk ? rc1 : rc0)];
#pragma unroll
          for (int qn = 0; qn < 2; ++qn) sf[tt][qn] = mfma16(kf, qf[qn][kk], sf[tt][qn]);
        }
      __builtin_amdgcn_s_setprio(0);

      const bool domask = (t0 + 63 > R0);
      if (domask) {
        const int tb = t0 + lg * 4;
#pragma unroll
        for (int tt = 0; tt < 4; ++tt)
#pragma unroll
          for (int qn = 0; qn < 2; ++qn) {
            const int qg = R0 + qn * 16 + l16;
#pragma unroll
            for (int j = 0; j < 4; ++j)
              if (tb + tt * 16 + j > qg) sf[tt][qn][j] = -INFINITY;
          }
      }

      float mx[2];
#pragma unroll
      for (int qn = 0; qn < 2; ++qn) {
        float m0 = sf[0][qn][0];
#pragma unroll
        for (int tt = 0; tt < 4; ++tt)
#pragma unroll
          for (int j = 0; j < 4; ++j) m0 = fmaxf(m0, sf[tt][qn][j]);
        m0 = fmaxf(m0, __shfl_xor(m0, 16, 64));
        m0 = fmaxf(m0, __shfl_xor(m0, 32, 64));
        mx[qn] = m0;
      }
      const int ok = (mx[0] <= m_[0] + 8.f) && (mx[1] <= m_[1] + 8.f);
      if (!__all(ok)) {
#pragma unroll
        for (int qn = 0; qn < 2; ++qn) {
          const float mnew = fmaxf(m_[qn], mx[qn]);
          const float rc = exp2f(m_[qn] - mnew);
          m_[qn] = mnew;
          l_[qn] *= rc;
#pragma unroll
          for (int hf = 0; hf < 4; ++hf)
#pragma unroll
            for (int j = 0; j < 4; ++j) oacc[qn][hf][j] *= rc;
        }
      }
#pragma unroll
      for (int qn = 0; qn < 2; ++qn) {
        float sum = 0.f;
#pragma unroll
        for (int tt = 0; tt < 4; ++tt)
#pragma unroll
          for (int j = 0; j < 4; ++j) {
            const float p = exp2f(sf[tt][qn][j] - m_[qn]);
            sf[tt][qn][j] = p;
            sum += p;
          }
        l_[qn] += sum;
      }

      // P -> per-wave LDS
#pragma unroll
      for (int qn = 0; qn < 2; ++qn)
#pragma unroll
        for (int tt = 0; tt < 4; ++tt) {
          const int ro = (qn * 16 + l16) * 72 + tt * 16 + lg * 4;
          *(unsigned*)&Psw[ro] = packbf2(sf[tt][qn][0], sf[tt][qn][1]);
          *(unsigned*)&Psw[ro + 2] = packbf2(sf[tt][qn][2], sf[tt][qn][3]);
        }

      // O^T += V^T P^T
      __builtin_amdgcn_s_setprio(1);
#pragma unroll
      for (int kk = 0; kk < 2; ++kk) {
        short8 pa[2];
#pragma unroll
        for (int qn = 0; qn < 2; ++qn)
          pa[qn] = *(const short8*)&Psw[(qn * 16 + l16) * 72 + kk * 32 + lg * 8];
#pragma unroll
        for (int hf = 0; hf < 4; ++hf) {
          short8 vf = *(const short8*)&Vts[(hf * 16 + l16) * 64 + (kk ? rc1 : rc0)];
#pragma unroll
          for (int qn = 0; qn < 2; ++qn)
            oacc[qn][hf] = mfma16(vf, pa[qn], oacc[qn][hf]);
        }
      }
      __builtin_amdgcn_s_setprio(0);
    }
  }

#pragma unroll
  for (int qn = 0; qn < 2; ++qn) {
    float lt = l_[qn];
    lt += __shfl_xor(lt, 16, 64);
    lt += __shfl_xor(lt, 32, 64);
    const float inv = 1.0f / lt;
    const long row = R0 + qn * 16 + l16;
#pragma unroll
    for (int hf = 0; hf < 4; ++hf) {
      short4v o4;
#pragma unroll
      for (int j = 0; j < 4; ++j) o4[j] = f2bf(oacc[qn][hf][j] * inv);
      *(short4v*)(att + ((long)b * SEQ + row) * D_MODEL + h * HSZ + hf * 16 + lg * 4) = o4;
    }
  }
}

// ---------------- launch ----------------
extern "C" void kernel_launch(void* const* d_in, const int* in_sizes, int n_in,
                              void* d_out, int out_size, void* d_ws, size_t ws_size,
                              hipStream_t stream) {
  const float* x = (const float*)d_in[0];
  const float* Wq = (const float*)d_in[1];
  const float* bq = (const float*)d_in[2];
  const float* Wk = (const float*)d_in[3];
  const float* bk = (const float*)d_in[4];
  const float* Wv = (const float*)d_in[5];
  const float* bv = (const float*)d_in[6];
  const float* Wp = (const float*)d_in[7];
  const float* bp = (const float*)d_in[8];
  const float* g1 = (const float*)d_in[9];
  const float* be1 = (const float*)d_in[10];
  const float* g2 = (const float*)d_in[11];
  const float* be2 = (const float*)d_in[12];
  const float* W1 = (const float*)d_in[13];
  const float* b1 = (const float*)d_in[14];
  const float* W2 = (const float*)d_in[15];
  const float* b2 = (const float*)d_in[16];
  float* out = (float*)d_out;
  char* ws = (char*)d_ws;

  if (ws_size < 209715200ull) return;

  short* WqkvT = (short*)(ws + 0);       // [3072][1024] bf16
  short* WpT = (short*)(ws + 6291456);   // [1024][1024]
  short* W1T = (short*)(ws + 8388608);   // [4096][1024]
  short* W2T = (short*)(ws + 16777216);  // [1024][4096]
  short* xn = (short*)(ws + 25165824);   // [8192][1024] (ln out; vt aliases after qkv)
  short* vt = (short*)(ws + 25165824);   // [B,H,HS,S] (aliases xn)
  short* qb = (short*)(ws + 41943040);   // [B,H,S,HS]
  short* kb = (short*)(ws + 58720256);
  short* vb = (short*)(ws + 75497472);
  short* att = (short*)(ws + 92274688);    // [8192][1024]
  float* x1 = (float*)(ws + 109051904);    // [8192][1024] f32
  short* hb = (short*)(ws + 142606336);    // [8192][4096]

  dim3 tb(32, 8);
  transpose_qkv_kernel<<<dim3(2, 32, 48), tb, 0, stream>>>(Wq, Wk, Wv, WqkvT);
  transpose_all_kernel<<<9216, tb, 0, stream>>>(Wp, WpT, W1, W1T, W2, W2T);
  ln_kernel<<<8192, 256, 0, stream>>>(x, g1, be1, xn);
  gemm_kernel<0, 128><<<dim3(12, 64), 512, 0, stream>>>(xn, WqkvT, 1024, bq, bk, bv,
                                                        nullptr, qb, kb, vb);
  v_transpose_kernel<<<dim3(32, 64), 256, 0, stream>>>(vb, vt);
  attn_kernel<<<dim3(64, 16), 256, 0, stream>>>(qb, kb, vt, att);
  gemm128_kernel<<<dim3(8, 64), 512, 0, stream>>>(att, WpT, 1024, bp, x, x1);
  ln_kernel<<<8192, 256, 0, stream>>>(x1, g2, be2, xn);
  gemm_kernel<2, 256><<<dim3(16, 32), 512, 0, stream>>>(xn, W1T, 1024, b1, nullptr,
                                                        nullptr, nullptr, hb, nullptr,
                                                        nullptr);
  gemm128_kernel<<<dim3(8, 64), 512, 0, stream>>>(hb, W2T, 4096, b2, x1, out);
}